// Round 1
// baseline (9458.127 us; speedup 1.0000x reference)
//
#include <hip/hip_runtime.h>
#include <hip/hip_bf16.h>
#include <math.h>

#define NTOK 2048
#define TSEQ 1024
#define DMODEL 768
#define NHEAD 12

__device__ __forceinline__ float wred64(float v) {
    v += __shfl_xor(v, 32);
    v += __shfl_xor(v, 16);
    v += __shfl_xor(v, 8);
    v += __shfl_xor(v, 4);
    v += __shfl_xor(v, 2);
    v += __shfl_xor(v, 1);
    return v;
}

__device__ __forceinline__ float siluf(float x) {
    return x / (1.f + expf(-x));
}

// ---------------- embedding + hash n-gram concat ----------------
__global__ __launch_bounds__(256) void embed_kernel(
    const int* __restrict__ ids, const float* __restrict__ tok,
    const float* __restrict__ bg, const float* __restrict__ tg,
    float* __restrict__ e) {
    int idx = blockIdx.x * 256 + threadIdx.x;
    if (idx >= NTOK * 832) return;
    int n = idx / 832, d = idx % 832;
    int t = n % TSEQ;
    int id = ids[n];
    if (d < 768) {
        e[(size_t)n * 832 + d] = tok[(size_t)id * 768 + d];
    } else {
        int j = d - 768;
        int prev  = (t >= 1) ? ids[n - 1] : 0;
        int prev2 = (t >= 2) ? ids[n - 2] : 0;
        int hb = (prev * 131 + id) % 32000;
        int ht = (prev2 * 173 + prev * 131 + id) % 32000;
        e[(size_t)n * 832 + d] = bg[(size_t)hb * 64 + j] + tg[(size_t)ht * 64 + j];
    }
}

// ---------------- rmsnorm (block per row) ----------------
__global__ __launch_bounds__(256) void rmsnorm_kernel(
    const float* __restrict__ in, float* __restrict__ out,
    const float* __restrict__ w, int D) {
    int row = blockIdx.x;
    const float* p = in + (size_t)row * D;
    float ss = 0.f;
    for (int d = threadIdx.x; d < D; d += 256) { float v = p[d]; ss += v * v; }
    ss = wred64(ss);
    __shared__ float lds[4];
    if ((threadIdx.x & 63) == 0) lds[threadIdx.x >> 6] = ss;
    __syncthreads();
    float tot = lds[0] + lds[1] + lds[2] + lds[3];
    float sc = rsqrtf(tot / D + 1e-6f);
    for (int d = threadIdx.x; d < D; d += 256) {
        float v = p[d] * sc;
        out[(size_t)row * D + d] = w ? v * w[d] : v;
    }
}

// ---------------- generic fp32 GEMM: C[M,N] = A[M,K] @ B[K,N] (row-major) ----------------
// EPI 0: C = acc ; EPI 1: C += scalePtr[scaleIdx]*acc
template <int EPI>
__global__ __launch_bounds__(256) void gemm_nn(
    const float* __restrict__ A, const float* __restrict__ B, float* __restrict__ C,
    int M, int Ncols, int K, const float* __restrict__ scalePtr, int scaleIdx) {
    __shared__ float As[16][68];
    __shared__ float Bs[16][64];
    int tid = threadIdx.x;
    int tx = tid & 15, ty = tid >> 4;
    int row0 = blockIdx.y * 64, col0 = blockIdx.x * 64;
    float acc[4][4] = {};
    int aR = tid >> 2;          // 0..63
    int aK = (tid & 3) * 4;     // 0,4,8,12
    int bK = tid >> 4;          // 0..15
    int bC = (tid & 15) * 4;
    const float* Ab = A + (size_t)(row0 + aR) * K + aK;
    const float* Bb = B + (size_t)bK * Ncols + col0 + bC;
    for (int k0 = 0; k0 < K; k0 += 16) {
        float4 a4 = *(const float4*)(Ab + k0);
        float4 b4 = *(const float4*)(Bb + (size_t)k0 * Ncols);
        __syncthreads();
        As[aK + 0][aR] = a4.x; As[aK + 1][aR] = a4.y;
        As[aK + 2][aR] = a4.z; As[aK + 3][aR] = a4.w;
        *(float4*)&Bs[bK][bC] = b4;
        __syncthreads();
#pragma unroll
        for (int kk = 0; kk < 16; kk++) {
            float4 av = *(const float4*)&As[kk][ty * 4];
            float4 bv = *(const float4*)&Bs[kk][tx * 4];
            float a_[4] = {av.x, av.y, av.z, av.w};
            float b_[4] = {bv.x, bv.y, bv.z, bv.w};
#pragma unroll
            for (int i = 0; i < 4; i++)
#pragma unroll
                for (int j = 0; j < 4; j++) acc[i][j] = fmaf(a_[i], b_[j], acc[i][j]);
        }
    }
    float s = (EPI == 1) ? scalePtr[scaleIdx] : 0.f;
#pragma unroll
    for (int i = 0; i < 4; i++) {
#pragma unroll
        for (int j = 0; j < 4; j++) {
            size_t idx = (size_t)(row0 + ty * 4 + i) * Ncols + col0 + tx * 4 + j;
            if (EPI == 0) C[idx] = acc[i][j];
            else          C[idx] += s * acc[i][j];
        }
    }
}

// ---------------- causal depthwise conv (K=4) + silu ----------------
__global__ __launch_bounds__(256) void conv_silu_kernel(
    const float* __restrict__ in, const float* __restrict__ w, float* __restrict__ out) {
    int idx = blockIdx.x * 256 + threadIdx.x;
    if (idx >= NTOK * 768) return;
    int n = idx / 768, c = idx % 768;
    int t = n % TSEQ;
    float acc = 0.f;
#pragma unroll
    for (int i = 0; i < 4; i++) {
        int ts = t - 3 + i;
        if (ts >= 0) acc = fmaf(w[c * 4 + i], in[(size_t)(n - 3 + i) * 768 + c], acc);
    }
    out[idx] = siluf(acc);
}

// ---------------- per-head l2 norm (wave per (n,h)) ----------------
__global__ __launch_bounds__(256) void headl2_kernel(float* __restrict__ buf, float mul) {
    int wid = threadIdx.x >> 6, lane = threadIdx.x & 63;
    int pair = blockIdx.x * 4 + wid;
    int n = pair / NHEAD, h = pair % NHEAD;
    size_t idx = (size_t)n * 768 + h * 64 + lane;
    float v = buf[idx];
    float ss = wred64(v * v);
    buf[idx] = v * rsqrtf(ss + 1e-6f) * mul;
}

// ---------------- beta / decay (wave per (n,h)) ----------------
__global__ __launch_bounds__(256) void betadecay_kernel(
    const float* __restrict__ xn, const float* __restrict__ Wb, const float* __restrict__ Wa,
    const float* __restrict__ Alog, const float* __restrict__ dtb,
    float* __restrict__ beta, float* __restrict__ decay) {
    int wid = threadIdx.x >> 6, lane = threadIdx.x & 63;
    int pair = blockIdx.x * 4 + wid;
    int n = pair / NHEAD, h = pair % NHEAD;
    const float* xr = xn + (size_t)n * 768;
    float pb = 0.f, pa = 0.f;
#pragma unroll
    for (int j = 0; j < 12; j++) {
        int d = lane + 64 * j;
        float xv = xr[d];
        pb = fmaf(xv, Wb[d * NHEAD + h], pb);
        pa = fmaf(xv, Wa[d * NHEAD + h], pa);
    }
    pb = wred64(pb);
    pa = wred64(pa);
    if (lane == 0) {
        beta[pair] = 1.f / (1.f + expf(-pb));
        float zz = pa + dtb[h];
        float sp = (zz > 20.f) ? zz : log1pf(expf(zz));
        float g = -expf(Alog[h]) * sp;
        decay[pair] = expf(g);
    }
}

// ---------------- gated delta-rule recurrence ----------------
// one block per (b,h); 256 threads: v = tid>>2 (column), kg = tid&3 (16 k rows each)
__global__ __launch_bounds__(256) void recur_kernel(
    const float* __restrict__ q, const float* __restrict__ k, const float* __restrict__ v,
    const float* __restrict__ beta, const float* __restrict__ decay, float* __restrict__ o) {
    int bh = blockIdx.x;
    int b = bh / NHEAD, h = bh % NHEAD;
    int tid = threadIdx.x;
    int vcol = tid >> 2, kg = tid & 3;
    int role = tid >> 6, lane = tid & 63;
    __shared__ float ksh[2][64], qsh[2][64], vsh[2][64], ssh[2][2];
    float S[16];
#pragma unroll
    for (int i = 0; i < 16; i++) S[i] = 0.f;
    // preload t=0
    {
        size_t n0 = (size_t)b * TSEQ;
        size_t base = n0 * 768 + h * 64;
        if (role == 0) ksh[0][lane] = k[base + lane];
        else if (role == 1) qsh[0][lane] = q[base + lane];
        else if (role == 2) vsh[0][lane] = v[base + lane];
        else {
            if (lane == 0) ssh[0][0] = beta[n0 * NHEAD + h];
            if (lane == 1) ssh[0][1] = decay[n0 * NHEAD + h];
        }
    }
    __syncthreads();
    for (int t = 0; t < TSEQ; t++) {
        int cur = t & 1, nxt = cur ^ 1;
        float pre = 0.f;
        bool hasNext = (t + 1 < TSEQ);
        if (hasNext) {
            size_t n1 = (size_t)b * TSEQ + t + 1;
            size_t base = n1 * 768 + h * 64;
            if (role == 0) pre = k[base + lane];
            else if (role == 1) pre = q[base + lane];
            else if (role == 2) pre = v[base + lane];
            else {
                if (lane == 0) pre = beta[n1 * NHEAD + h];
                if (lane == 1) pre = decay[n1 * NHEAD + h];
            }
        }
        float bet = ssh[cur][0], dec = ssh[cur][1];
        float kr[16];
#pragma unroll
        for (int i = 0; i < 16; i++) kr[i] = ksh[cur][kg * 16 + i];
        float m[16];
#pragma unroll
        for (int i = 0; i < 16; i++) m[i] = S[i] * kr[i];
        float p = (((m[0] + m[1]) + (m[2] + m[3])) + ((m[4] + m[5]) + (m[6] + m[7]))) +
                  (((m[8] + m[9]) + (m[10] + m[11])) + ((m[12] + m[13]) + (m[14] + m[15])));
        p += __shfl_xor(p, 1);
        p += __shfl_xor(p, 2);
        float kv = dec * p;
        float dv = bet * (vsh[cur][vcol] - kv);
#pragma unroll
        for (int i = 0; i < 16; i++) S[i] = fmaf(dec, S[i], kr[i] * dv);
        float qr, m2[16];
#pragma unroll
        for (int i = 0; i < 16; i++) { qr = qsh[cur][kg * 16 + i]; m2[i] = S[i] * qr; }
        float p2 = (((m2[0] + m2[1]) + (m2[2] + m2[3])) + ((m2[4] + m2[5]) + (m2[6] + m2[7]))) +
                   (((m2[8] + m2[9]) + (m2[10] + m2[11])) + ((m2[12] + m2[13]) + (m2[14] + m2[15])));
        p2 += __shfl_xor(p2, 1);
        p2 += __shfl_xor(p2, 2);
        if (kg == 0) o[((size_t)b * TSEQ + t) * 768 + h * 64 + vcol] = p2;
        if (hasNext) {
            if (role == 0) ksh[nxt][lane] = pre;
            else if (role == 1) qsh[nxt][lane] = pre;
            else if (role == 2) vsh[nxt][lane] = pre;
            else {
                if (lane == 0) ssh[nxt][0] = pre;
                if (lane == 1) ssh[nxt][1] = pre;
            }
        }
        __syncthreads();
    }
}

// ---------------- o rmsnorm * silu(gate) ----------------
__global__ __launch_bounds__(256) void onormgate_kernel(
    float* __restrict__ o, const float* __restrict__ gate, const float* __restrict__ onw) {
    int wid = threadIdx.x >> 6, lane = threadIdx.x & 63;
    int pair = blockIdx.x * 4 + wid;
    int n = pair / NHEAD, h = pair % NHEAD;
    size_t idx = (size_t)n * 768 + h * 64 + lane;
    float v = o[idx];
    float ms = wred64(v * v) * (1.f / 64.f);
    float y = v * rsqrtf(ms + 1e-6f) * onw[lane];
    float g = gate[idx];
    o[idx] = y * siluf(g);
}

// ---------------- silu(u) * v for MLP ----------------
__global__ __launch_bounds__(256) void silumul_kernel(
    const float* __restrict__ uv, float* __restrict__ hb) {
    int idx = blockIdx.x * 256 + threadIdx.x;
    if (idx >= NTOK * 3072) return;
    int n = idx / 3072, j = idx % 3072;
    float u = uv[(size_t)n * 6144 + j];
    float vv = uv[(size_t)n * 6144 + 3072 + j];
    hb[idx] = siluf(u) * vv;
}

// ---------------- fused logits + sum-exp (softcap bounds logits, no max needed) ----------------
__global__ __launch_bounds__(256) void logits_kernel(
    const float* __restrict__ Xf, const float* __restrict__ Emb, float* __restrict__ Z) {
    __shared__ float As[64][17];
    __shared__ float Es[128][17];
    __shared__ float rowsum[64];
    int tid = threadIdx.x;
    int tx = tid & 15, ty = tid >> 4;
    int row0 = blockIdx.y * 64, col0 = blockIdx.x * 128;
    if (tid < 64) rowsum[tid] = 0.f;
    float acc[4][8] = {};
    int aR = tid >> 2, aK = (tid & 3) * 4;
    int eV = tid >> 1, eK = (tid & 1) * 8;
    const float* Ab = Xf + (size_t)(row0 + aR) * 768 + aK;
    const float* Eb = Emb + (size_t)(col0 + eV) * 768 + eK;
    for (int k0 = 0; k0 < 768; k0 += 16) {
        float4 a4 = *(const float4*)(Ab + k0);
        float4 e4 = *(const float4*)(Eb + k0);
        float4 e4b = *(const float4*)(Eb + k0 + 4);
        __syncthreads();
        As[aR][aK + 0] = a4.x; As[aR][aK + 1] = a4.y;
        As[aR][aK + 2] = a4.z; As[aR][aK + 3] = a4.w;
        Es[eV][eK + 0] = e4.x; Es[eV][eK + 1] = e4.y;
        Es[eV][eK + 2] = e4.z; Es[eV][eK + 3] = e4.w;
        Es[eV][eK + 4] = e4b.x; Es[eV][eK + 5] = e4b.y;
        Es[eV][eK + 6] = e4b.z; Es[eV][eK + 7] = e4b.w;
        __syncthreads();
#pragma unroll
        for (int kk = 0; kk < 16; kk++) {
            float a_[4], e_[8];
#pragma unroll
            for (int i = 0; i < 4; i++) a_[i] = As[ty + 16 * i][kk];
#pragma unroll
            for (int j = 0; j < 8; j++) e_[j] = Es[tx + 16 * j][kk];
#pragma unroll
            for (int i = 0; i < 4; i++)
#pragma unroll
                for (int j = 0; j < 8; j++) acc[i][j] = fmaf(a_[i], e_[j], acc[i][j]);
        }
    }
#pragma unroll
    for (int i = 0; i < 4; i++) {
        float rp = 0.f;
#pragma unroll
        for (int j = 0; j < 8; j++) {
            float lg = 30.f * tanhf(acc[i][j] * (1.f / 30.f));
            rp += expf(lg);
        }
        atomicAdd(&rowsum[ty + 16 * i], rp);
    }
    __syncthreads();
    if (tid < 64) atomicAdd(&Z[row0 + tid], rowsum[tid]);
}

// ---------------- target logit (wave per row) ----------------
__global__ __launch_bounds__(256) void target_kernel(
    const float* __restrict__ xf, const float* __restrict__ emb,
    const int* __restrict__ tids, float* __restrict__ tgt) {
    int wid = threadIdx.x >> 6, lane = threadIdx.x & 63;
    int r = blockIdx.x * 4 + wid;
    int tg = tids[r];
    float p = 0.f;
#pragma unroll
    for (int j = 0; j < 12; j++) {
        int d = lane + 64 * j;
        p = fmaf(xf[(size_t)r * 768 + d], emb[(size_t)tg * 768 + d], p);
    }
    p = wred64(p);
    if (lane == 0) tgt[r] = 30.f * tanhf(p * (1.f / 30.f));
}

// ---------------- final NLL mean ----------------
__global__ __launch_bounds__(256) void final_reduce(
    const float* __restrict__ Z, const float* __restrict__ tgt, float* __restrict__ out) {
    __shared__ float lds[4];
    int tid = threadIdx.x;
    float p = 0.f;
    for (int r = tid; r < NTOK; r += 256) p += logf(Z[r]) - tgt[r];
    p = wred64(p);
    if ((tid & 63) == 0) lds[tid >> 6] = p;
    __syncthreads();
    if (tid == 0) out[0] = (lds[0] + lds[1] + lds[2] + lds[3]) * (1.f / NTOK);
}

extern "C" void kernel_launch(void* const* d_in, const int* in_sizes, int n_in,
                              void* d_out, int out_size, void* d_ws, size_t ws_size,
                              hipStream_t stream) {
    const float* tok_emb      = (const float*)d_in[0];
    const float* bigram_w     = (const float*)d_in[1];
    const float* tri_w        = (const float*)d_in[2];
    const float* embed_proj_w = (const float*)d_in[3];
    const float* attn_norm_w  = (const float*)d_in[4];
    const float* mlp_norm_w   = (const float*)d_in[5];
    const float* Wq           = (const float*)d_in[6];
    const float* Wk           = (const float*)d_in[7];
    const float* Wv           = (const float*)d_in[8];
    const float* Wb           = (const float*)d_in[9];
    const float* Wa           = (const float*)d_in[10];
    const float* A_log        = (const float*)d_in[11];
    const float* dt_bias      = (const float*)d_in[12];
    const float* conv_q       = (const float*)d_in[13];
    const float* conv_k       = (const float*)d_in[14];
    const float* conv_v       = (const float*)d_in[15];
    const float* Wg           = (const float*)d_in[16];
    const float* o_norm_w     = (const float*)d_in[17];
    const float* Wo           = (const float*)d_in[18];
    const float* attn_scale   = (const float*)d_in[19];
    const float* mlp_scale    = (const float*)d_in[20];
    const float* mlp_fc_w     = (const float*)d_in[21];
    const float* mlp_proj_w   = (const float*)d_in[22];
    const float* final_norm_w = (const float*)d_in[23];
    const int*   input_ids    = (const int*)d_in[24];
    const int*   target_ids   = (const int*)d_in[25];
    float* out = (float*)d_out;

    const size_t NT = NTOK;
    float* ws    = (float*)d_ws;
    float* x     = ws;                        // NT*768
    float* xn    = x + NT * 768;              // NT*768
    float* bufA  = xn + NT * 768;             // NT*6144
    float* bufB  = bufA + NT * 6144;          // NT*3072
    float* beta  = bufB + NT * 3072;          // NT*12
    float* decay = beta + NT * 12;            // NT*12
    float* Zrow  = decay + NT * 12;           // NT
    float* tgt   = Zrow + NT;                 // NT

    // embedding
    embed_kernel<<<(NTOK * 832 + 255) / 256, 256, 0, stream>>>(input_ids, tok_emb, bigram_w, tri_w, bufA);
    gemm_nn<0><<<dim3(12, 32), 256, 0, stream>>>(bufA, embed_proj_w, x, 2048, 768, 832, nullptr, 0);
    rmsnorm_kernel<<<NTOK, 256, 0, stream>>>(x, x, nullptr, 768);

    for (int l = 0; l < 4; l++) {
        const float* Wq_l = Wq + (size_t)l * 768 * 768;
        const float* Wk_l = Wk + (size_t)l * 768 * 768;
        const float* Wv_l = Wv + (size_t)l * 768 * 768;
        const float* Wg_l = Wg + (size_t)l * 768 * 768;
        const float* Wo_l = Wo + (size_t)l * 768 * 768;
        float* qp = bufA;
        float* kp = bufA + NT * 768;
        float* vp = bufA + 2 * NT * 768;
        float* qc = bufB;
        float* kc = bufB + NT * 768;
        float* vc = bufB + 2 * NT * 768;
        float* gate = bufB + 3 * NT * 768; // fits: bufB is NT*3072 wait... (uses last NT*768 of NT*3072? 3*768=2304, +768=3072 OK)

        rmsnorm_kernel<<<NTOK, 256, 0, stream>>>(x, xn, attn_norm_w + l * 768, 768);
        gemm_nn<0><<<dim3(12, 32), 256, 0, stream>>>(xn, Wq_l, qp, 2048, 768, 768, nullptr, 0);
        gemm_nn<0><<<dim3(12, 32), 256, 0, stream>>>(xn, Wk_l, kp, 2048, 768, 768, nullptr, 0);
        gemm_nn<0><<<dim3(12, 32), 256, 0, stream>>>(xn, Wv_l, vp, 2048, 768, 768, nullptr, 0);
        gemm_nn<0><<<dim3(12, 32), 256, 0, stream>>>(xn, Wg_l, gate, 2048, 768, 768, nullptr, 0);
        conv_silu_kernel<<<6144, 256, 0, stream>>>(qp, conv_q + (size_t)l * 768 * 4, qc);
        conv_silu_kernel<<<6144, 256, 0, stream>>>(kp, conv_k + (size_t)l * 768 * 4, kc);
        conv_silu_kernel<<<6144, 256, 0, stream>>>(vp, conv_v + (size_t)l * 768 * 4, vc);
        headl2_kernel<<<6144, 256, 0, stream>>>(qc, 0.125f);
        headl2_kernel<<<6144, 256, 0, stream>>>(kc, 1.f);
        betadecay_kernel<<<6144, 256, 0, stream>>>(xn, Wb + (size_t)l * 768 * 12, Wa + (size_t)l * 768 * 12,
                                                   A_log + l * 12, dt_bias + l * 12, beta, decay);
        recur_kernel<<<24, 256, 0, stream>>>(qc, kc, vc, beta, decay, bufA);
        onormgate_kernel<<<6144, 256, 0, stream>>>(bufA, gate, o_norm_w + l * 64);
        gemm_nn<1><<<dim3(12, 32), 256, 0, stream>>>(bufA, Wo_l, x, 2048, 768, 768, attn_scale, l);

        rmsnorm_kernel<<<NTOK, 256, 0, stream>>>(x, xn, mlp_norm_w + l * 768, 768);
        gemm_nn<0><<<dim3(96, 32), 256, 0, stream>>>(xn, mlp_fc_w + (size_t)l * 768 * 6144, bufA, 2048, 6144, 768, nullptr, 0);
        silumul_kernel<<<24576, 256, 0, stream>>>(bufA, bufB);
        gemm_nn<1><<<dim3(12, 32), 256, 0, stream>>>(bufB, mlp_proj_w + (size_t)l * 3072 * 768, x, 2048, 768, 3072, mlp_scale, l);
    }

    rmsnorm_kernel<<<NTOK, 256, 0, stream>>>(x, xn, final_norm_w, 768);
    hipMemsetAsync(Zrow, 0, NTOK * sizeof(float), stream);
    logits_kernel<<<dim3(250, 32), 256, 0, stream>>>(xn, tok_emb, Zrow);
    target_kernel<<<512, 256, 0, stream>>>(xn, tok_emb, target_ids, tgt);
    final_reduce<<<1, 256, 0, stream>>>(Zrow, tgt, out);
}

// Round 2
// 5836.929 us; speedup vs baseline: 1.6204x; 1.6204x over previous
//
#include <hip/hip_runtime.h>
#include <math.h>

#define NTOK 2048
#define TSEQ 1024
#define NHEAD 12

typedef unsigned short u16;
typedef unsigned int u32;
typedef __bf16 bf16x8 __attribute__((ext_vector_type(8)));
typedef float f32x4 __attribute__((ext_vector_type(4)));

__device__ __forceinline__ u16 f2b(float f) {
    u32 x = __float_as_uint(f);
    return (u16)((x + 0x7fffu + ((x >> 16) & 1u)) >> 16);
}
__device__ __forceinline__ float b2f(u16 u) {
    return __uint_as_float(((u32)u) << 16);
}
__device__ __forceinline__ void gload16(const void* g, void* l) {
    __builtin_amdgcn_global_load_lds((const __attribute__((address_space(1))) u32*)g,
                                     (__attribute__((address_space(3))) u32*)l, 16, 0, 0);
}
__device__ __forceinline__ float wred64(float v) {
    v += __shfl_xor(v, 32); v += __shfl_xor(v, 16); v += __shfl_xor(v, 8);
    v += __shfl_xor(v, 4);  v += __shfl_xor(v, 2);  v += __shfl_xor(v, 1);
    return v;
}
__device__ __forceinline__ float siluf(float x) { return x / (1.f + __expf(-x)); }

// ---------------- fp32 -> bf16 bulk convert (8/thread) ----------------
__global__ __launch_bounds__(256) void cvt_bf16(const float* __restrict__ in, u16* __restrict__ out, int n8) {
    int i = blockIdx.x * 256 + threadIdx.x;
    if (i >= n8) return;
    float4 a = ((const float4*)in)[i * 2];
    float4 b = ((const float4*)in)[i * 2 + 1];
    uint4 o;
    o.x = (u32)f2b(a.x) | ((u32)f2b(a.y) << 16);
    o.y = (u32)f2b(a.z) | ((u32)f2b(a.w) << 16);
    o.z = (u32)f2b(b.x) | ((u32)f2b(b.y) << 16);
    o.w = (u32)f2b(b.z) | ((u32)f2b(b.w) << 16);
    ((uint4*)out)[i] = o;
}

// ---------------- transpose + convert: in [R][C] fp32 -> out [C][R] bf16 ----------------
__global__ __launch_bounds__(256) void transcvt(const float* __restrict__ in, u16* __restrict__ out, int R, int C) {
    __shared__ float t[32][33];
    int c0 = blockIdx.x * 32, r0 = blockIdx.y * 32;
    int tx = threadIdx.x & 31, ty = threadIdx.x >> 5;
#pragma unroll
    for (int i = 0; i < 32; i += 8) t[ty + i][tx] = in[(size_t)(r0 + ty + i) * C + c0 + tx];
    __syncthreads();
#pragma unroll
    for (int i = 0; i < 32; i += 8) out[(size_t)(c0 + ty + i) * R + r0 + tx] = f2b(t[tx][ty + i]);
}

// ---------------- embedding + hash n-gram concat (bf16 out) ----------------
__global__ __launch_bounds__(256) void embed_kernel(
    const int* __restrict__ ids, const float* __restrict__ tok,
    const float* __restrict__ bg, const float* __restrict__ tg, u16* __restrict__ e) {
    int idx = blockIdx.x * 256 + threadIdx.x;
    if (idx >= NTOK * 832) return;
    int n = idx / 832, d = idx % 832;
    int t = n % TSEQ;
    int id = ids[n];
    float v;
    if (d < 768) {
        v = tok[(size_t)id * 768 + d];
    } else {
        int j = d - 768;
        int prev  = (t >= 1) ? ids[n - 1] : 0;
        int prev2 = (t >= 2) ? ids[n - 2] : 0;
        int hb = (prev * 131 + id) % 32000;
        int ht = (prev2 * 173 + prev * 131 + id) % 32000;
        v = bg[(size_t)hb * 64 + j] + tg[(size_t)ht * 64 + j];
    }
    e[(size_t)n * 832 + d] = f2b(v);
}

// ---------------- rmsnorm fp32->fp32 (no weight) ----------------
__global__ __launch_bounds__(256) void rmsnorm_f32(const float* __restrict__ in, float* __restrict__ out, int D) {
    int row = blockIdx.x;
    const float* p = in + (size_t)row * D;
    float ss = 0.f;
    for (int d = threadIdx.x; d < D; d += 256) { float v = p[d]; ss += v * v; }
    ss = wred64(ss);
    __shared__ float lds[4];
    if ((threadIdx.x & 63) == 0) lds[threadIdx.x >> 6] = ss;
    __syncthreads();
    float sc = rsqrtf((lds[0] + lds[1] + lds[2] + lds[3]) / D + 1e-6f);
    for (int d = threadIdx.x; d < D; d += 256) out[(size_t)row * D + d] = p[d] * sc;
}

// ---------------- rmsnorm fp32->bf16 (weighted) ----------------
__global__ __launch_bounds__(256) void rmsnorm_bf(const float* __restrict__ in, u16* __restrict__ out,
                                                  const float* __restrict__ w, int D) {
    int row = blockIdx.x;
    const float* p = in + (size_t)row * D;
    float ss = 0.f;
    for (int d = threadIdx.x; d < D; d += 256) { float v = p[d]; ss += v * v; }
    ss = wred64(ss);
    __shared__ float lds[4];
    if ((threadIdx.x & 63) == 0) lds[threadIdx.x >> 6] = ss;
    __syncthreads();
    float sc = rsqrtf((lds[0] + lds[1] + lds[2] + lds[3]) / D + 1e-6f);
    for (int d = threadIdx.x; d < D; d += 256) out[(size_t)row * D + d] = f2b(p[d] * sc * w[d]);
}

// ---------------- bf16 MFMA GEMM: C[M,N] = A[M,K] @ BT[N,K]^T ----------------
// EPI 0: C = acc ; EPI 1: C += scalePtr[scaleIdx]*acc ; EPI 2: logits row-sum into Z
template <int EPI>
__global__ __launch_bounds__(256) void gemm_bf(
    const u16* __restrict__ A, const u16* __restrict__ BT, float* __restrict__ C,
    int M, int N, int K, const float* __restrict__ scalePtr, int scaleIdx,
    float* __restrict__ Z) {
    __shared__ u16 Asb[128 * 32];
    __shared__ u16 Bsb[128 * 32];
    __shared__ float rowsum[128];
    const int tid = threadIdx.x;
    const int w = tid >> 6, lane = tid & 63;
    const int row0 = blockIdx.y * 128, col0 = blockIdx.x * 128;
    if (EPI == 2 && tid < 128) rowsum[tid] = 0.f;
    const int wr = w >> 1, wc = w & 1;
    const int fr = lane & 15, fq = lane >> 4;
    f32x4 acc[4][4];
#pragma unroll
    for (int m = 0; m < 4; m++)
#pragma unroll
        for (int n = 0; n < 4; n++) acc[m][n] = f32x4{0.f, 0.f, 0.f, 0.f};
    const int sr = lane >> 2;        // staging row within a 16-row chunk
    const int sk = (lane & 3) * 8;   // staging k element offset
    const u16* Ag0 = A + (size_t)(row0 + w * 32 + sr) * K + sk;
    const u16* Ag1 = Ag0 + (size_t)16 * K;
    const u16* Bg0 = BT + (size_t)(col0 + w * 32 + sr) * K + sk;
    const u16* Bg1 = Bg0 + (size_t)16 * K;
    u16* Al0 = &Asb[(w * 32) * 32];
    u16* Al1 = Al0 + 16 * 32;
    u16* Bl0 = &Bsb[(w * 32) * 32];
    u16* Bl1 = Bl0 + 16 * 32;
    for (int k0 = 0; k0 < K; k0 += 32) {
        gload16(Ag0, Al0); gload16(Ag1, Al1);
        gload16(Bg0, Bl0); gload16(Bg1, Bl1);
        Ag0 += 32; Ag1 += 32; Bg0 += 32; Bg1 += 32;
        __syncthreads();
        bf16x8 af[4], bfr[4];
#pragma unroll
        for (int m = 0; m < 4; m++)
            af[m] = *(const bf16x8*)&Asb[(wr * 64 + m * 16 + fr) * 32 + fq * 8];
#pragma unroll
        for (int n = 0; n < 4; n++)
            bfr[n] = *(const bf16x8*)&Bsb[(wc * 64 + n * 16 + fr) * 32 + fq * 8];
#pragma unroll
        for (int m = 0; m < 4; m++)
#pragma unroll
            for (int n = 0; n < 4; n++)
                acc[m][n] = __builtin_amdgcn_mfma_f32_16x16x32_bf16(af[m], bfr[n], acc[m][n], 0, 0, 0);
        __syncthreads();
    }
    if (EPI == 2) {
#pragma unroll
        for (int m = 0; m < 4; m++) {
#pragma unroll
            for (int r = 0; r < 4; r++) {
                float p = 0.f;
#pragma unroll
                for (int n = 0; n < 4; n++) {
                    float v = acc[m][n][r];
                    float e2 = __expf(v * (2.f / 30.f));
                    float th = 1.f - 2.f / (1.f + e2);      // tanh(v/30)
                    p += __expf(30.f * th);
                }
                p += __shfl_xor(p, 1);
                p += __shfl_xor(p, 2);
                p += __shfl_xor(p, 4);
                p += __shfl_xor(p, 8);
                if (fr == 0) atomicAdd(&rowsum[wr * 64 + m * 16 + fq * 4 + r], p);
            }
        }
        __syncthreads();
        if (tid < 128) atomicAdd(&Z[row0 + tid], rowsum[tid]);
    } else {
        float s = (EPI == 1) ? scalePtr[scaleIdx] : 0.f;
#pragma unroll
        for (int m = 0; m < 4; m++)
#pragma unroll
            for (int n = 0; n < 4; n++)
#pragma unroll
                for (int r = 0; r < 4; r++) {
                    size_t idx = (size_t)(row0 + wr * 64 + m * 16 + fq * 4 + r) * N +
                                 col0 + wc * 64 + n * 16 + fr;
                    if (EPI == 0) C[idx] = acc[m][n][r];
                    else          C[idx] += s * acc[m][n][r];
                }
    }
}

// ---------------- causal depthwise conv (K=4) + silu; input has leading dim ld ----------------
__global__ __launch_bounds__(256) void conv_silu_kernel(
    const float* __restrict__ in, int ld, const float* __restrict__ w, float* __restrict__ out) {
    int idx = blockIdx.x * 256 + threadIdx.x;
    if (idx >= NTOK * 768) return;
    int n = idx / 768, c = idx % 768;
    int t = n % TSEQ;
    float acc = 0.f;
#pragma unroll
    for (int i = 0; i < 4; i++) {
        int ts = t - 3 + i;
        if (ts >= 0) acc = fmaf(w[c * 4 + i], in[(size_t)(n - 3 + i) * ld + c], acc);
    }
    out[idx] = siluf(acc);
}

// ---------------- per-head l2 norm (wave per (n,h)) ----------------
__global__ __launch_bounds__(256) void headl2_kernel(float* __restrict__ buf, float mul) {
    int wid = threadIdx.x >> 6, lane = threadIdx.x & 63;
    int pair = blockIdx.x * 4 + wid;
    size_t idx = (size_t)(pair / NHEAD) * 768 + (pair % NHEAD) * 64 + lane;
    float v = buf[idx];
    float ss = wred64(v * v);
    buf[idx] = v * rsqrtf(ss + 1e-6f) * mul;
}

// ---------------- beta / decay (wave per (n,h)) ----------------
__global__ __launch_bounds__(256) void betadecay_kernel(
    const u16* __restrict__ xn, const float* __restrict__ Wb, const float* __restrict__ Wa,
    const float* __restrict__ Alog, const float* __restrict__ dtb,
    float* __restrict__ beta, float* __restrict__ decay) {
    int wid = threadIdx.x >> 6, lane = threadIdx.x & 63;
    int pair = blockIdx.x * 4 + wid;
    int n = pair / NHEAD, h = pair % NHEAD;
    const u16* xr = xn + (size_t)n * 768;
    float pb = 0.f, pa = 0.f;
#pragma unroll
    for (int j = 0; j < 12; j++) {
        int d = lane + 64 * j;
        float xv = b2f(xr[d]);
        pb = fmaf(xv, Wb[d * NHEAD + h], pb);
        pa = fmaf(xv, Wa[d * NHEAD + h], pa);
    }
    pb = wred64(pb);
    pa = wred64(pa);
    if (lane == 0) {
        beta[pair] = 1.f / (1.f + expf(-pb));
        float zz = pa + dtb[h];
        float sp = (zz > 20.f) ? zz : log1pf(expf(zz));
        decay[pair] = expf(-expf(Alog[h]) * sp);
    }
}

// ---------------- gated delta-rule recurrence (block per (b,h)) ----------------
__global__ __launch_bounds__(256) void recur_kernel(
    const float* __restrict__ q, const float* __restrict__ k, const float* __restrict__ v,
    const float* __restrict__ beta, const float* __restrict__ decay, float* __restrict__ o) {
    int bh = blockIdx.x;
    int b = bh / NHEAD, h = bh % NHEAD;
    int tid = threadIdx.x;
    int vcol = tid >> 2, kg = tid & 3;
    int role = tid >> 6, lane = tid & 63;
    __shared__ float ksh[2][64], qsh[2][64], vsh[2][64], ssh[2][2];
    float S[16];
#pragma unroll
    for (int i = 0; i < 16; i++) S[i] = 0.f;
    {
        size_t n0 = (size_t)b * TSEQ;
        size_t base = n0 * 768 + h * 64;
        if (role == 0) ksh[0][lane] = k[base + lane];
        else if (role == 1) qsh[0][lane] = q[base + lane];
        else if (role == 2) vsh[0][lane] = v[base + lane];
        else {
            if (lane == 0) ssh[0][0] = beta[n0 * NHEAD + h];
            if (lane == 1) ssh[0][1] = decay[n0 * NHEAD + h];
        }
    }
    __syncthreads();
    for (int t = 0; t < TSEQ; t++) {
        int cur = t & 1, nxt = cur ^ 1;
        float pre = 0.f;
        bool hasNext = (t + 1 < TSEQ);
        if (hasNext) {
            size_t n1 = (size_t)b * TSEQ + t + 1;
            size_t base = n1 * 768 + h * 64;
            if (role == 0) pre = k[base + lane];
            else if (role == 1) pre = q[base + lane];
            else if (role == 2) pre = v[base + lane];
            else {
                if (lane == 0) pre = beta[n1 * NHEAD + h];
                if (lane == 1) pre = decay[n1 * NHEAD + h];
            }
        }
        float bet = ssh[cur][0], dec = ssh[cur][1];
        float kr[16];
#pragma unroll
        for (int i = 0; i < 16; i++) kr[i] = ksh[cur][kg * 16 + i];
        float m[16];
#pragma unroll
        for (int i = 0; i < 16; i++) m[i] = S[i] * kr[i];
        float p = (((m[0] + m[1]) + (m[2] + m[3])) + ((m[4] + m[5]) + (m[6] + m[7]))) +
                  (((m[8] + m[9]) + (m[10] + m[11])) + ((m[12] + m[13]) + (m[14] + m[15])));
        p += __shfl_xor(p, 1);
        p += __shfl_xor(p, 2);
        float kv = dec * p;
        float dv = bet * (vsh[cur][vcol] - kv);
#pragma unroll
        for (int i = 0; i < 16; i++) S[i] = fmaf(dec, S[i], kr[i] * dv);
        float m2[16];
#pragma unroll
        for (int i = 0; i < 16; i++) m2[i] = S[i] * qsh[cur][kg * 16 + i];
        float p2 = (((m2[0] + m2[1]) + (m2[2] + m2[3])) + ((m2[4] + m2[5]) + (m2[6] + m2[7]))) +
                   (((m2[8] + m2[9]) + (m2[10] + m2[11])) + ((m2[12] + m2[13]) + (m2[14] + m2[15])));
        p2 += __shfl_xor(p2, 1);
        p2 += __shfl_xor(p2, 2);
        if (kg == 0) o[((size_t)b * TSEQ + t) * 768 + h * 64 + vcol] = p2;
        if (hasNext) {
            if (role == 0) ksh[nxt][lane] = pre;
            else if (role == 1) qsh[nxt][lane] = pre;
            else if (role == 2) vsh[nxt][lane] = pre;
            else {
                if (lane == 0) ssh[nxt][0] = pre;
                if (lane == 1) ssh[nxt][1] = pre;
            }
        }
        __syncthreads();
    }
}

// ---------------- o rmsnorm * silu(gate) -> bf16 ----------------
__global__ __launch_bounds__(256) void onormgate_kernel(
    const float* __restrict__ o, const float* __restrict__ gate, int gld,
    const float* __restrict__ onw, u16* __restrict__ obf) {
    int wid = threadIdx.x >> 6, lane = threadIdx.x & 63;
    int pair = blockIdx.x * 4 + wid;
    int n = pair / NHEAD, h = pair % NHEAD;
    size_t idx = (size_t)n * 768 + h * 64 + lane;
    float v = o[idx];
    float ms = wred64(v * v) * (1.f / 64.f);
    float y = v * rsqrtf(ms + 1e-6f) * onw[lane];
    float g = gate[(size_t)n * gld + h * 64 + lane];
    obf[idx] = f2b(y * siluf(g));
}

// ---------------- silu(u) * v -> bf16 ----------------
__global__ __launch_bounds__(256) void silumul_kernel(const float* __restrict__ uv, u16* __restrict__ hb) {
    int idx = blockIdx.x * 256 + threadIdx.x;
    if (idx >= NTOK * 3072) return;
    int n = idx / 3072, j = idx % 3072;
    float u = uv[(size_t)n * 6144 + j];
    float vv = uv[(size_t)n * 6144 + 3072 + j];
    hb[idx] = f2b(siluf(u) * vv);
}

// ---------------- target logit (wave per row) ----------------
__global__ __launch_bounds__(256) void target_kernel(
    const u16* __restrict__ xf, const u16* __restrict__ emb,
    const int* __restrict__ tids, float* __restrict__ tgt) {
    int wid = threadIdx.x >> 6, lane = threadIdx.x & 63;
    int r = blockIdx.x * 4 + wid;
    int tg = tids[r];
    float p = 0.f;
#pragma unroll
    for (int j = 0; j < 12; j++) {
        int d = lane + 64 * j;
        p = fmaf(b2f(xf[(size_t)r * 768 + d]), b2f(emb[(size_t)tg * 768 + d]), p);
    }
    p = wred64(p);
    if (lane == 0) {
        float e2 = __expf(p * (2.f / 30.f));
        tgt[r] = 30.f * (1.f - 2.f / (1.f + e2));
    }
}

// ---------------- final NLL mean ----------------
__global__ __launch_bounds__(256) void final_reduce(
    const float* __restrict__ Z, const float* __restrict__ tgt, float* __restrict__ out) {
    __shared__ float lds[4];
    int tid = threadIdx.x;
    float p = 0.f;
    for (int r = tid; r < NTOK; r += 256) p += logf(Z[r]) - tgt[r];
    p = wred64(p);
    if ((tid & 63) == 0) lds[tid >> 6] = p;
    __syncthreads();
    if (tid == 0) out[0] = (lds[0] + lds[1] + lds[2] + lds[3]) * (1.f / NTOK);
}

extern "C" void kernel_launch(void* const* d_in, const int* in_sizes, int n_in,
                              void* d_out, int out_size, void* d_ws, size_t ws_size,
                              hipStream_t stream) {
    const float* tok_emb      = (const float*)d_in[0];
    const float* bigram_w     = (const float*)d_in[1];
    const float* tri_w        = (const float*)d_in[2];
    const float* embed_proj_w = (const float*)d_in[3];
    const float* attn_norm_w  = (const float*)d_in[4];
    const float* mlp_norm_w   = (const float*)d_in[5];
    const float* Wq           = (const float*)d_in[6];
    const float* Wk           = (const float*)d_in[7];
    const float* Wv           = (const float*)d_in[8];
    const float* Wb           = (const float*)d_in[9];
    const float* Wa           = (const float*)d_in[10];
    const float* A_log        = (const float*)d_in[11];
    const float* dt_bias      = (const float*)d_in[12];
    const float* conv_q       = (const float*)d_in[13];
    const float* conv_k       = (const float*)d_in[14];
    const float* conv_v       = (const float*)d_in[15];
    const float* Wg           = (const float*)d_in[16];
    const float* o_norm_w     = (const float*)d_in[17];
    const float* Wo           = (const float*)d_in[18];
    const float* attn_scale   = (const float*)d_in[19];
    const float* mlp_scale    = (const float*)d_in[20];
    const float* mlp_fc_w     = (const float*)d_in[21];
    const float* mlp_proj_w   = (const float*)d_in[22];
    const float* final_norm_w = (const float*)d_in[23];
    const int*   input_ids    = (const int*)d_in[24];
    const int*   target_ids   = (const int*)d_in[25];
    float* out = (float*)d_out;

    const size_t NT = NTOK;
    float* x     = (float*)d_ws;              // NT*768
    float* bufA  = x + NT * 768;              // NT*6144
    float* qc    = bufA + NT * 6144;          // NT*768
    float* kc    = qc + NT * 768;
    float* vc    = kc + NT * 768;
    float* obuf  = vc + NT * 768;
    float* beta  = obuf + NT * 768;           // NT*12
    float* decay = beta + NT * 12;            // NT*12
    float* Zrow  = decay + NT * 12;           // NT
    float* tgt   = Zrow + NT;                 // NT
    u16* xn_bf = (u16*)(tgt + NT);            // NT*768
    u16* e_bf  = xn_bf + NT * 768;            // NT*832
    u16* h_bf  = e_bf + NT * 832;             // NT*3072
    u16* o_bf  = h_bf + NT * 3072;            // NT*768
    u16* wT    = o_bf + NT * 768;             // 6144*768 max
    u16* embT  = wT + (size_t)6144 * 768;     // 32000*768

    // ---- upfront conversions ----
    cvt_bf16<<<12000, 256, 0, stream>>>(tok_emb, embT, 32000 * 768 / 8);
    transcvt<<<dim3(24, 26), 256, 0, stream>>>(embed_proj_w, wT, 832, 768);

    // ---- embedding ----
    embed_kernel<<<(NTOK * 832 + 255) / 256, 256, 0, stream>>>(input_ids, tok_emb, bigram_w, tri_w, e_bf);
    gemm_bf<0><<<dim3(6, 16), 256, 0, stream>>>(e_bf, wT, x, 2048, 768, 832, nullptr, 0, nullptr);
    rmsnorm_f32<<<NTOK, 256, 0, stream>>>(x, x, 768);

    for (int l = 0; l < 4; l++) {
        const float* WL[4] = {Wq + (size_t)l * 768 * 768, Wk + (size_t)l * 768 * 768,
                              Wv + (size_t)l * 768 * 768, Wg + (size_t)l * 768 * 768};
        rmsnorm_bf<<<NTOK, 256, 0, stream>>>(x, xn_bf, attn_norm_w + l * 768, 768);
        for (int i = 0; i < 4; i++)
            transcvt<<<dim3(24, 24), 256, 0, stream>>>(WL[i], wT + (size_t)i * 768 * 768, 768, 768);
        gemm_bf<0><<<dim3(24, 16), 256, 0, stream>>>(xn_bf, wT, bufA, 2048, 3072, 768, nullptr, 0, nullptr);
        conv_silu_kernel<<<6144, 256, 0, stream>>>(bufA,        3072, conv_q + (size_t)l * 768 * 4, qc);
        conv_silu_kernel<<<6144, 256, 0, stream>>>(bufA + 768,  3072, conv_k + (size_t)l * 768 * 4, kc);
        conv_silu_kernel<<<6144, 256, 0, stream>>>(bufA + 1536, 3072, conv_v + (size_t)l * 768 * 4, vc);
        headl2_kernel<<<6144, 256, 0, stream>>>(qc, 0.125f);
        headl2_kernel<<<6144, 256, 0, stream>>>(kc, 1.f);
        betadecay_kernel<<<6144, 256, 0, stream>>>(xn_bf, Wb + (size_t)l * 768 * 12, Wa + (size_t)l * 768 * 12,
                                                   A_log + l * 12, dt_bias + l * 12, beta, decay);
        recur_kernel<<<24, 256, 0, stream>>>(qc, kc, vc, beta, decay, obuf);
        onormgate_kernel<<<6144, 256, 0, stream>>>(obuf, bufA + 2304, 3072, o_norm_w + l * 64, o_bf);
        transcvt<<<dim3(24, 24), 256, 0, stream>>>(Wo + (size_t)l * 768 * 768, wT, 768, 768);
        gemm_bf<1><<<dim3(6, 16), 256, 0, stream>>>(o_bf, wT, x, 2048, 768, 768, attn_scale, l, nullptr);

        rmsnorm_bf<<<NTOK, 256, 0, stream>>>(x, xn_bf, mlp_norm_w + l * 768, 768);
        transcvt<<<dim3(192, 24), 256, 0, stream>>>(mlp_fc_w + (size_t)l * 768 * 6144, wT, 768, 6144);
        gemm_bf<0><<<dim3(48, 16), 256, 0, stream>>>(xn_bf, wT, bufA, 2048, 6144, 768, nullptr, 0, nullptr);
        silumul_kernel<<<24576, 256, 0, stream>>>(bufA, h_bf);
        transcvt<<<dim3(24, 96), 256, 0, stream>>>(mlp_proj_w + (size_t)l * 3072 * 768, wT, 3072, 768);
        gemm_bf<1><<<dim3(6, 16), 256, 0, stream>>>(h_bf, wT, x, 2048, 768, 3072, mlp_scale, l, nullptr);
    }

    rmsnorm_bf<<<NTOK, 256, 0, stream>>>(x, xn_bf, final_norm_w, 768);
    hipMemsetAsync(Zrow, 0, NTOK * sizeof(float), stream);
    gemm_bf<2><<<dim3(250, 16), 256, 0, stream>>>(xn_bf, embT, nullptr, 2048, 32000, 768, nullptr, 0, Zrow);
    target_kernel<<<512, 256, 0, stream>>>(xn_bf, embT, target_ids, tgt);
    final_reduce<<<1, 256, 0, stream>>>(Zrow, tgt, out);
}

// Round 5
// 3216.859 us; speedup vs baseline: 2.9402x; 1.8145x over previous
//
#include <hip/hip_runtime.h>
#include <math.h>

#define NTOK 2048
#define TSEQ 1024
#define NHEAD 12

typedef unsigned short u16;
typedef unsigned int u32;
typedef __bf16 bf16x8 __attribute__((ext_vector_type(8)));
typedef float f32x4 __attribute__((ext_vector_type(4)));

__device__ __forceinline__ u16 f2b(float f) {
    u32 x = __float_as_uint(f);
    return (u16)((x + 0x7fffu + ((x >> 16) & 1u)) >> 16);
}
__device__ __forceinline__ float b2f(u16 u) {
    return __uint_as_float(((u32)u) << 16);
}
__device__ __forceinline__ void gload16(const void* g, void* l) {
    __builtin_amdgcn_global_load_lds((const __attribute__((address_space(1))) u32*)g,
                                     (__attribute__((address_space(3))) u32*)l, 16, 0, 0);
}
__device__ __forceinline__ float wred64(float v) {
    v += __shfl_xor(v, 32); v += __shfl_xor(v, 16); v += __shfl_xor(v, 8);
    v += __shfl_xor(v, 4);  v += __shfl_xor(v, 2);  v += __shfl_xor(v, 1);
    return v;
}
__device__ __forceinline__ float siluf(float x) { return x / (1.f + __expf(-x)); }

// ---------------- fp32 -> bf16 bulk convert (8/thread) ----------------
__global__ __launch_bounds__(256) void cvt_bf16(const float* __restrict__ in, u16* __restrict__ out, int n8) {
    int i = blockIdx.x * 256 + threadIdx.x;
    if (i >= n8) return;
    float4 a = ((const float4*)in)[i * 2];
    float4 b = ((const float4*)in)[i * 2 + 1];
    uint4 o;
    o.x = (u32)f2b(a.x) | ((u32)f2b(a.y) << 16);
    o.y = (u32)f2b(a.z) | ((u32)f2b(a.w) << 16);
    o.z = (u32)f2b(b.x) | ((u32)f2b(b.y) << 16);
    o.w = (u32)f2b(b.z) | ((u32)f2b(b.w) << 16);
    ((uint4*)out)[i] = o;
}

// ---------------- transpose + convert: in [R][C] fp32 -> out [C][R] bf16 ----------------
__global__ __launch_bounds__(256) void transcvt(const float* __restrict__ in, u16* __restrict__ out, int R, int C) {
    __shared__ float t[32][33];
    int c0 = blockIdx.x * 32, r0 = blockIdx.y * 32;
    int tx = threadIdx.x & 31, ty = threadIdx.x >> 5;
#pragma unroll
    for (int i = 0; i < 32; i += 8) t[ty + i][tx] = in[(size_t)(r0 + ty + i) * C + c0 + tx];
    __syncthreads();
#pragma unroll
    for (int i = 0; i < 32; i += 8) out[(size_t)(c0 + ty + i) * R + r0 + tx] = f2b(t[tx][ty + i]);
}

// ---------------- embedding + hash n-gram concat (bf16 out) ----------------
__global__ __launch_bounds__(256) void embed_kernel(
    const int* __restrict__ ids, const float* __restrict__ tok,
    const float* __restrict__ bg, const float* __restrict__ tg, u16* __restrict__ e) {
    int idx = blockIdx.x * 256 + threadIdx.x;
    if (idx >= NTOK * 832) return;
    int n = idx / 832, d = idx % 832;
    int t = n % TSEQ;
    int id = ids[n];
    float v;
    if (d < 768) {
        v = tok[(size_t)id * 768 + d];
    } else {
        int j = d - 768;
        int prev  = (t >= 1) ? ids[n - 1] : 0;
        int prev2 = (t >= 2) ? ids[n - 2] : 0;
        int hb = (prev * 131 + id) % 32000;
        int ht = (prev2 * 173 + prev * 131 + id) % 32000;
        v = bg[(size_t)hb * 64 + j] + tg[(size_t)ht * 64 + j];
    }
    e[(size_t)n * 832 + d] = f2b(v);
}

// ---------------- rmsnorm fp32->fp32 (no weight) ----------------
__global__ __launch_bounds__(256) void rmsnorm_f32(const float* __restrict__ in, float* __restrict__ out, int D) {
    int row = blockIdx.x;
    const float* p = in + (size_t)row * D;
    float ss = 0.f;
    for (int d = threadIdx.x; d < D; d += 256) { float v = p[d]; ss += v * v; }
    ss = wred64(ss);
    __shared__ float lds[4];
    if ((threadIdx.x & 63) == 0) lds[threadIdx.x >> 6] = ss;
    __syncthreads();
    float sc = rsqrtf((lds[0] + lds[1] + lds[2] + lds[3]) / D + 1e-6f);
    for (int d = threadIdx.x; d < D; d += 256) out[(size_t)row * D + d] = p[d] * sc;
}

// ---------------- rmsnorm fp32->bf16 (weighted) ----------------
__global__ __launch_bounds__(256) void rmsnorm_bf(const float* __restrict__ in, u16* __restrict__ out,
                                                  const float* __restrict__ w, int D) {
    int row = blockIdx.x;
    const float* p = in + (size_t)row * D;
    float ss = 0.f;
    for (int d = threadIdx.x; d < D; d += 256) { float v = p[d]; ss += v * v; }
    ss = wred64(ss);
    __shared__ float lds[4];
    if ((threadIdx.x & 63) == 0) lds[threadIdx.x >> 6] = ss;
    __syncthreads();
    float sc = rsqrtf((lds[0] + lds[1] + lds[2] + lds[3]) / D + 1e-6f);
    for (int d = threadIdx.x; d < D; d += 256) out[(size_t)row * D + d] = f2b(p[d] * sc * w[d]);
}

// ---------------- bf16 MFMA GEMM: C[M,N] = A[M,K] @ BT[N,K]^T ----------------
template <int EPI>
__global__ __launch_bounds__(256) void gemm_bf(
    const u16* __restrict__ A, const u16* __restrict__ BT, float* __restrict__ C,
    int M, int N, int K, const float* __restrict__ scalePtr, int scaleIdx,
    float* __restrict__ Z) {
    __shared__ u16 Asb[128 * 32];
    __shared__ u16 Bsb[128 * 32];
    __shared__ float rowsum[128];
    const int tid = threadIdx.x;
    const int w = tid >> 6, lane = tid & 63;
    const int row0 = blockIdx.y * 128, col0 = blockIdx.x * 128;
    if (EPI == 2 && tid < 128) rowsum[tid] = 0.f;
    const int wr = w >> 1, wc = w & 1;
    const int fr = lane & 15, fq = lane >> 4;
    f32x4 acc[4][4];
#pragma unroll
    for (int m = 0; m < 4; m++)
#pragma unroll
        for (int n = 0; n < 4; n++) acc[m][n] = f32x4{0.f, 0.f, 0.f, 0.f};
    const int sr = lane >> 2;
    const int sk = (lane & 3) * 8;
    const u16* Ag0 = A + (size_t)(row0 + w * 32 + sr) * K + sk;
    const u16* Ag1 = Ag0 + (size_t)16 * K;
    const u16* Bg0 = BT + (size_t)(col0 + w * 32 + sr) * K + sk;
    const u16* Bg1 = Bg0 + (size_t)16 * K;
    u16* Al0 = &Asb[(w * 32) * 32];
    u16* Al1 = Al0 + 16 * 32;
    u16* Bl0 = &Bsb[(w * 32) * 32];
    u16* Bl1 = Bl0 + 16 * 32;
    for (int k0 = 0; k0 < K; k0 += 32) {
        gload16(Ag0, Al0); gload16(Ag1, Al1);
        gload16(Bg0, Bl0); gload16(Bg1, Bl1);
        Ag0 += 32; Ag1 += 32; Bg0 += 32; Bg1 += 32;
        __syncthreads();
        bf16x8 af[4], bfr[4];
#pragma unroll
    for (int m = 0; m < 4; m++)
            af[m] = *(const bf16x8*)&Asb[(wr * 64 + m * 16 + fr) * 32 + fq * 8];
#pragma unroll
        for (int n = 0; n < 4; n++)
            bfr[n] = *(const bf16x8*)&Bsb[(wc * 64 + n * 16 + fr) * 32 + fq * 8];
#pragma unroll
        for (int m = 0; m < 4; m++)
#pragma unroll
            for (int n = 0; n < 4; n++)
                acc[m][n] = __builtin_amdgcn_mfma_f32_16x16x32_bf16(af[m], bfr[n], acc[m][n], 0, 0, 0);
        __syncthreads();
    }
    if (EPI == 2) {
#pragma unroll
        for (int m = 0; m < 4; m++) {
#pragma unroll
            for (int r = 0; r < 4; r++) {
                float p = 0.f;
#pragma unroll
                for (int n = 0; n < 4; n++) {
                    float v = acc[m][n][r];
                    float e2 = __expf(v * (2.f / 30.f));
                    float th = 1.f - 2.f / (1.f + e2);
                    p += __expf(30.f * th);
                }
                p += __shfl_xor(p, 1);
                p += __shfl_xor(p, 2);
                p += __shfl_xor(p, 4);
                p += __shfl_xor(p, 8);
                if (fr == 0) atomicAdd(&rowsum[wr * 64 + m * 16 + fq * 4 + r], p);
            }
        }
        __syncthreads();
        if (tid < 128) atomicAdd(&Z[row0 + tid], rowsum[tid]);
    } else {
        float s = (EPI == 1) ? scalePtr[scaleIdx] : 0.f;
#pragma unroll
        for (int m = 0; m < 4; m++)
#pragma unroll
            for (int n = 0; n < 4; n++)
#pragma unroll
                for (int r = 0; r < 4; r++) {
                    size_t idx = (size_t)(row0 + wr * 64 + m * 16 + fq * 4 + r) * N +
                                 col0 + wc * 64 + n * 16 + fr;
                    if (EPI == 0) C[idx] = acc[m][n][r];
                    else          C[idx] += s * acc[m][n][r];
                }
    }
}

// ---------------- causal depthwise conv (K=4) + silu ----------------
__global__ __launch_bounds__(256) void conv_silu_kernel(
    const float* __restrict__ in, int ld, const float* __restrict__ w, float* __restrict__ out) {
    int idx = blockIdx.x * 256 + threadIdx.x;
    if (idx >= NTOK * 768) return;
    int n = idx / 768, c = idx % 768;
    int t = n % TSEQ;
    float acc = 0.f;
#pragma unroll
    for (int i = 0; i < 4; i++) {
        int ts = t - 3 + i;
        if (ts >= 0) acc = fmaf(w[c * 4 + i], in[(size_t)(n - 3 + i) * ld + c], acc);
    }
    out[idx] = siluf(acc);
}

// ---------------- per-head l2 norm ----------------
__global__ __launch_bounds__(256) void headl2_kernel(float* __restrict__ buf, float mul) {
    int wid = threadIdx.x >> 6, lane = threadIdx.x & 63;
    int pair = blockIdx.x * 4 + wid;
    size_t idx = (size_t)(pair / NHEAD) * 768 + (pair % NHEAD) * 64 + lane;
    float v = buf[idx];
    float ss = wred64(v * v);
    buf[idx] = v * rsqrtf(ss + 1e-6f) * mul;
}

// ---------------- beta / log-decay g (wave per (n,h)) ----------------
__global__ __launch_bounds__(256) void betadecay_kernel(
    const u16* __restrict__ xn, const float* __restrict__ Wb, const float* __restrict__ Wa,
    const float* __restrict__ Alog, const float* __restrict__ dtb,
    float* __restrict__ beta, float* __restrict__ glog) {
    int wid = threadIdx.x >> 6, lane = threadIdx.x & 63;
    int pair = blockIdx.x * 4 + wid;
    int n = pair / NHEAD, h = pair % NHEAD;
    const u16* xr = xn + (size_t)n * 768;
    float pb = 0.f, pa = 0.f;
#pragma unroll
    for (int j = 0; j < 12; j++) {
        int d = lane + 64 * j;
        float xv = b2f(xr[d]);
        pb = fmaf(xv, Wb[d * NHEAD + h], pb);
        pa = fmaf(xv, Wa[d * NHEAD + h], pa);
    }
    pb = wred64(pb);
    pa = wred64(pa);
    if (lane == 0) {
        beta[pair] = 1.f / (1.f + expf(-pb));
        float zz = pa + dtb[h];
        float sp = (zz > 20.f) ? zz : log1pf(expf(zz));
        glog[pair] = -expf(Alog[h]) * sp;   // store g (log-space decay)
    }
}

// ================= chunked gated delta rule =================
// P1: per (chunk, bh): build M, forward-substitute for [U_local | W]
__global__ __launch_bounds__(256) void p1_kernel(
    const float* __restrict__ kc, const float* __restrict__ vc,
    const float* __restrict__ beta, const float* __restrict__ glog,
    float* __restrict__ Wg, float* __restrict__ Ug, float* __restrict__ Gg) {
    int c = blockIdx.x, bh = blockIdx.y;
    int b = bh / NHEAD, h = bh % NHEAD;
    int n0 = b * TSEQ + c * 64;
    __shared__ float Ksh[64][66];
    __shared__ float Msh[64][66];
    __shared__ float UW[64][130];
    __shared__ float Gsh[64], Bsh[64], Esh[64];
    int tid = threadIdx.x;
    for (int idx = tid; idx < 4096; idx += 256) {
        int t = idx >> 6, i = idx & 63;
        Ksh[t][i] = kc[(size_t)(n0 + t) * 768 + h * 64 + i];
    }
    if (tid < 64) {
        Bsh[tid] = beta[(size_t)(n0 + tid) * NHEAD + h];
        float val = glog[(size_t)(n0 + tid) * NHEAD + h];
#pragma unroll
        for (int off = 1; off < 64; off <<= 1) {
            float o_ = __shfl_up(val, off);
            if (tid >= off) val += o_;
        }
        Gsh[tid] = val;
        Esh[tid] = __expf(val);
    }
    __syncthreads();
    // strict-lower M and RHS fill
    for (int idx = tid; idx < 4096; idx += 256) {
        int t = idx >> 6, s = idx & 63;
        if (s < t) {
            float d = 0.f;
#pragma unroll 8
            for (int i = 0; i < 64; i++) d += Ksh[t][i] * Ksh[s][i];
            Msh[t][s] = d * __expf(Gsh[t] - Gsh[s]);
        }
        UW[t][s]      = Bsh[t] * vc[(size_t)(n0 + t) * 768 + h * 64 + s];
        UW[t][64 + s] = Bsh[t] * Esh[t] * Ksh[t][s];
    }
    __syncthreads();
    // forward substitution over 128 columns, 2 threads/column
    int col = tid >> 1, half = tid & 1;
    for (int t = 1; t < 64; t++) {
        float s = 0.f;
        for (int ss = half; ss < t; ss += 2) s += Msh[t][ss] * UW[ss][col];
        s += __shfl_xor(s, 1);
        if (half == 0) UW[t][col] -= Bsh[t] * s;
        __syncthreads();
    }
    size_t base = ((size_t)bh * 16 + c) * 4096;
    for (int idx = tid; idx < 4096; idx += 256) {
        int t = idx >> 6, j = idx & 63;
        Ug[base + idx] = UW[t][j];
        Wg[base + idx] = UW[t][64 + j];
    }
    if (tid < 64) Gg[((size_t)bh * 16 + c) * 64 + tid] = Gsh[tid];
}

// P2: per (vslice, bh): 16 sequential chunk steps; S kept in LDS
__global__ __launch_bounds__(256) void p2_kernel(
    const float* __restrict__ qc, const float* __restrict__ kc,
    const float* __restrict__ Wg, float* __restrict__ Ug, const float* __restrict__ Gg,
    float* __restrict__ obuf) {
    int j0 = blockIdx.x * 16, bh = blockIdx.y;
    int b = bh / NHEAD, h = bh % NHEAD;
    __shared__ float Ssh[64][17];
    __shared__ float Big[64][66];
    __shared__ float Ush[64][17];
    __shared__ float Gsh[64], Esh[64];
    int tid = threadIdx.x;
    int j = tid & 15, tg = tid >> 4;
#pragma unroll
    for (int r = 0; r < 4; r++) Ssh[tg + 16 * r][j] = 0.f;
    __syncthreads();
    for (int c = 0; c < 16; c++) {
        int n0 = b * TSEQ + c * 64;
        size_t gbase = ((size_t)bh * 16 + c) * 4096;
        if (tid < 64) {
            float gv = Gg[((size_t)bh * 16 + c) * 64 + tid];
            Gsh[tid] = gv;
            Esh[tid] = __expf(gv);
        }
        for (int idx = tid; idx < 4096; idx += 256) {
            int t = idx >> 6, i = idx & 63;
            Big[t][i] = qc[(size_t)(n0 + t) * 768 + h * 64 + i];
        }
        for (int idx = tid; idx < 1024; idx += 256) {
            int t = idx >> 4, jj = idx & 15;
            Ush[t][jj] = Ug[gbase + t * 64 + j0 + jj];
        }
        __syncthreads();
        // (a) O1 = diag(gamma) Q @ S
#pragma unroll
        for (int r = 0; r < 4; r++) {
            int t = tg + 16 * r;
            float acc = 0.f;
#pragma unroll 8
            for (int i = 0; i < 64; i++) acc += Big[t][i] * Ssh[i][j];
            obuf[(size_t)(n0 + t) * 768 + h * 64 + j0 + j] = Esh[t] * acc;
        }
        __syncthreads();
        for (int idx = tid; idx < 4096; idx += 256) {
            int t = idx >> 6, i = idx & 63;
            Big[t][i] = Wg[gbase + idx];
        }
        __syncthreads();
        // (b) U = U_local - W @ S
        float uvals[4];
#pragma unroll
        for (int r = 0; r < 4; r++) {
            int t = tg + 16 * r;
            float acc = 0.f;
#pragma unroll 8
            for (int i = 0; i < 64; i++) acc += Big[t][i] * Ssh[i][j];
            uvals[r] = Ush[t][j] - acc;
            Ug[gbase + t * 64 + j0 + j] = uvals[r];
        }
#pragma unroll
        for (int r = 0; r < 4; r++) Ush[tg + 16 * r][j] = uvals[r];
        __syncthreads();
        // stage Ktil = exp(G_C - G_t) * k_t
        for (int idx = tid; idx < 4096; idx += 256) {
            int t = idx >> 6, i = idx & 63;
            Big[t][i] = __expf(Gsh[63] - Gsh[t]) * kc[(size_t)(n0 + t) * 768 + h * 64 + i];
        }
        __syncthreads();
        // (c) S = gamma_C * S + Ktil^T @ U
        float gc = Esh[63];
#pragma unroll
        for (int r = 0; r < 4; r++) {
            int i = tg + 16 * r;
            float acc = 0.f;
#pragma unroll 8
            for (int t = 0; t < 64; t++) acc += Big[t][i] * Ush[t][j];
            Ssh[i][j] = gc * Ssh[i][j] + acc;
        }
        __syncthreads();
    }
}

// P3: per (chunk, bh): O += tril_incl((q_t.k_s) e^{G_t-G_s}) @ U
__global__ __launch_bounds__(256) void p3_kernel(
    const float* __restrict__ qc, const float* __restrict__ kc,
    const float* __restrict__ Ug, const float* __restrict__ Gg, float* __restrict__ obuf) {
    int c = blockIdx.x, bh = blockIdx.y;
    int b = bh / NHEAD, h = bh % NHEAD;
    int n0 = b * TSEQ + c * 64;
    size_t gbase = ((size_t)bh * 16 + c) * 4096;
    __shared__ float Qsh[64][66];
    __shared__ float Ksh[64][66];
    __shared__ float Ash[64][66];
    __shared__ float Gsh[64];
    int tid = threadIdx.x;
    if (tid < 64) Gsh[tid] = Gg[((size_t)bh * 16 + c) * 64 + tid];
    for (int idx = tid; idx < 4096; idx += 256) {
        int t = idx >> 6, i = idx & 63;
        Qsh[t][i] = qc[(size_t)(n0 + t) * 768 + h * 64 + i];
        Ksh[t][i] = kc[(size_t)(n0 + t) * 768 + h * 64 + i];
    }
    __syncthreads();
    for (int idx = tid; idx < 4096; idx += 256) {
        int t = idx >> 6, s = idx & 63;
        if (s <= t) {
            float d = 0.f;
#pragma unroll 8
            for (int i = 0; i < 64; i++) d += Qsh[t][i] * Ksh[s][i];
            Ash[t][s] = d * __expf(Gsh[t] - Gsh[s]);
        } else {
            Ash[t][s] = 0.f;
        }
    }
    __syncthreads();
    for (int idx = tid; idx < 4096; idx += 256) {
        int t = idx >> 6, jj = idx & 63;
        Qsh[t][jj] = Ug[gbase + idx];
    }
    __syncthreads();
    for (int idx = tid; idx < 4096; idx += 256) {
        int t = idx >> 6, jj = idx & 63;
        float acc = 0.f;
#pragma unroll 8
        for (int s = 0; s < 64; s++) acc += Ash[t][s] * Qsh[s][jj];
        obuf[(size_t)(n0 + t) * 768 + h * 64 + jj] += acc;
    }
}

// ---------------- o rmsnorm * silu(gate) -> bf16 ----------------
__global__ __launch_bounds__(256) void onormgate_kernel(
    const float* __restrict__ o, const float* __restrict__ gate, int gld,
    const float* __restrict__ onw, u16* __restrict__ obf) {
    int wid = threadIdx.x >> 6, lane = threadIdx.x & 63;
    int pair = blockIdx.x * 4 + wid;
    int n = pair / NHEAD, h = pair % NHEAD;
    size_t idx = (size_t)n * 768 + h * 64 + lane;
    float v = o[idx];
    float ms = wred64(v * v) * (1.f / 64.f);
    float y = v * rsqrtf(ms + 1e-6f) * onw[lane];
    float g = gate[(size_t)n * gld + h * 64 + lane];
    obf[idx] = f2b(y * siluf(g));
}

// ---------------- silu(u) * v -> bf16 ----------------
__global__ __launch_bounds__(256) void silumul_kernel(const float* __restrict__ uv, u16* __restrict__ hb) {
    int idx = blockIdx.x * 256 + threadIdx.x;
    if (idx >= NTOK * 3072) return;
    int n = idx / 3072, j = idx % 3072;
    float u = uv[(size_t)n * 6144 + j];
    float vv = uv[(size_t)n * 6144 + 3072 + j];
    hb[idx] = f2b(siluf(u) * vv);
}

// ---------------- target logit (wave per row) ----------------
__global__ __launch_bounds__(256) void target_kernel(
    const u16* __restrict__ xf, const u16* __restrict__ emb,
    const int* __restrict__ tids, float* __restrict__ tgt) {
    int wid = threadIdx.x >> 6, lane = threadIdx.x & 63;
    int r = blockIdx.x * 4 + wid;
    int tg = tids[r];
    float p = 0.f;
#pragma unroll
    for (int j = 0; j < 12; j++) {
        int d = lane + 64 * j;
        p = fmaf(b2f(xf[(size_t)r * 768 + d]), b2f(emb[(size_t)tg * 768 + d]), p);
    }
    p = wred64(p);
    if (lane == 0) {
        float e2 = __expf(p * (2.f / 30.f));
        tgt[r] = 30.f * (1.f - 2.f / (1.f + e2));
    }
}

// ---------------- final NLL mean ----------------
__global__ __launch_bounds__(256) void final_reduce(
    const float* __restrict__ Z, const float* __restrict__ tgt, float* __restrict__ out) {
    __shared__ float lds[4];
    int tid = threadIdx.x;
    float p = 0.f;
    for (int r = tid; r < NTOK; r += 256) p += logf(Z[r]) - tgt[r];
    p = wred64(p);
    if ((tid & 63) == 0) lds[tid >> 6] = p;
    __syncthreads();
    if (tid == 0) out[0] = (lds[0] + lds[1] + lds[2] + lds[3]) * (1.f / NTOK);
}

extern "C" void kernel_launch(void* const* d_in, const int* in_sizes, int n_in,
                              void* d_out, int out_size, void* d_ws, size_t ws_size,
                              hipStream_t stream) {
    const float* tok_emb      = (const float*)d_in[0];
    const float* bigram_w     = (const float*)d_in[1];
    const float* tri_w        = (const float*)d_in[2];
    const float* embed_proj_w = (const float*)d_in[3];
    const float* attn_norm_w  = (const float*)d_in[4];
    const float* mlp_norm_w   = (const float*)d_in[5];
    const float* Wq           = (const float*)d_in[6];
    const float* Wk           = (const float*)d_in[7];
    const float* Wv           = (const float*)d_in[8];
    const float* Wb           = (const float*)d_in[9];
    const float* Wa           = (const float*)d_in[10];
    const float* A_log        = (const float*)d_in[11];
    const float* dt_bias      = (const float*)d_in[12];
    const float* conv_q       = (const float*)d_in[13];
    const float* conv_k       = (const float*)d_in[14];
    const float* conv_v       = (const float*)d_in[15];
    const float* Wg_in        = (const float*)d_in[16];
    const float* o_norm_w     = (const float*)d_in[17];
    const float* Wo           = (const float*)d_in[18];
    const float* attn_scale   = (const float*)d_in[19];
    const float* mlp_scale    = (const float*)d_in[20];
    const float* mlp_fc_w     = (const float*)d_in[21];
    const float* mlp_proj_w   = (const float*)d_in[22];
    const float* final_norm_w = (const float*)d_in[23];
    const int*   input_ids    = (const int*)d_in[24];
    const int*   target_ids   = (const int*)d_in[25];
    float* out = (float*)d_out;

    const size_t NT = NTOK;
    float* x     = (float*)d_ws;              // NT*768
    float* bufA  = x + NT * 768;              // NT*6144
    float* qc    = bufA + NT * 6144;          // NT*768
    float* kc    = qc + NT * 768;
    float* vc    = kc + NT * 768;
    float* obuf  = vc + NT * 768;
    float* beta  = obuf + NT * 768;           // NT*12
    float* glog  = beta + NT * 12;            // NT*12
    float* Zrow  = glog + NT * 12;            // NT
    float* tgt   = Zrow + NT;                 // NT
    u16* xn_bf = (u16*)(tgt + NT);            // NT*768
    u16* e_bf  = xn_bf + NT * 768;            // NT*832
    u16* h_bf  = e_bf + NT * 832;             // NT*3072
    u16* o_bf  = h_bf + NT * 3072;            // NT*768
    u16* wT    = o_bf + NT * 768;             // 6144*768 max
    u16* embT  = wT + (size_t)6144 * 768;     // 32000*768
    float* Wg  = (float*)(embT + (size_t)32000 * 768);  // 24*16*4096
    float* Ug  = Wg + (size_t)24 * 16 * 4096;           // 24*16*4096
    float* Gg  = Ug + (size_t)24 * 16 * 4096;           // 24*16*64

    // ---- upfront conversions ----
    cvt_bf16<<<12000, 256, 0, stream>>>(tok_emb, embT, 32000 * 768 / 8);
    transcvt<<<dim3(24, 26), 256, 0, stream>>>(embed_proj_w, wT, 832, 768);

    // ---- embedding ----
    embed_kernel<<<(NTOK * 832 + 255) / 256, 256, 0, stream>>>(input_ids, tok_emb, bigram_w, tri_w, e_bf);
    gemm_bf<0><<<dim3(6, 16), 256, 0, stream>>>(e_bf, wT, x, 2048, 768, 832, nullptr, 0, nullptr);
    rmsnorm_f32<<<NTOK, 256, 0, stream>>>(x, x, 768);

    for (int l = 0; l < 4; l++) {
        const float* WL[4] = {Wq + (size_t)l * 768 * 768, Wk + (size_t)l * 768 * 768,
                              Wv + (size_t)l * 768 * 768, Wg_in + (size_t)l * 768 * 768};
        rmsnorm_bf<<<NTOK, 256, 0, stream>>>(x, xn_bf, attn_norm_w + l * 768, 768);
        for (int i = 0; i < 4; i++)
            transcvt<<<dim3(24, 24), 256, 0, stream>>>(WL[i], wT + (size_t)i * 768 * 768, 768, 768);
        gemm_bf<0><<<dim3(24, 16), 256, 0, stream>>>(xn_bf, wT, bufA, 2048, 3072, 768, nullptr, 0, nullptr);
        conv_silu_kernel<<<6144, 256, 0, stream>>>(bufA,        3072, conv_q + (size_t)l * 768 * 4, qc);
        conv_silu_kernel<<<6144, 256, 0, stream>>>(bufA + 768,  3072, conv_k + (size_t)l * 768 * 4, kc);
        conv_silu_kernel<<<6144, 256, 0, stream>>>(bufA + 1536, 3072, conv_v + (size_t)l * 768 * 4, vc);
        headl2_kernel<<<6144, 256, 0, stream>>>(qc, 0.125f);
        headl2_kernel<<<6144, 256, 0, stream>>>(kc, 1.f);
        betadecay_kernel<<<6144, 256, 0, stream>>>(xn_bf, Wb + (size_t)l * 768 * 12, Wa + (size_t)l * 768 * 12,
                                                   A_log + l * 12, dt_bias + l * 12, beta, glog);
        p1_kernel<<<dim3(16, 24), 256, 0, stream>>>(kc, vc, beta, glog, Wg, Ug, Gg);
        p2_kernel<<<dim3(4, 24), 256, 0, stream>>>(qc, kc, Wg, Ug, Gg, obuf);
        p3_kernel<<<dim3(16, 24), 256, 0, stream>>>(qc, kc, Ug, Gg, obuf);
        onormgate_kernel<<<6144, 256, 0, stream>>>(obuf, bufA + 2304, 3072, o_norm_w + l * 64, o_bf);
        transcvt<<<dim3(24, 24), 256, 0, stream>>>(Wo + (size_t)l * 768 * 768, wT, 768, 768);
        gemm_bf<1><<<dim3(6, 16), 256, 0, stream>>>(o_bf, wT, x, 2048, 768, 768, attn_scale, l, nullptr);

        rmsnorm_bf<<<NTOK, 256, 0, stream>>>(x, xn_bf, mlp_norm_w + l * 768, 768);
        transcvt<<<dim3(192, 24), 256, 0, stream>>>(mlp_fc_w + (size_t)l * 768 * 6144, wT, 768, 6144);
        gemm_bf<0><<<dim3(48, 16), 256, 0, stream>>>(xn_bf, wT, bufA, 2048, 6144, 768, nullptr, 0, nullptr);
        silumul_kernel<<<24576, 256, 0, stream>>>(bufA, h_bf);
        transcvt<<<dim3(24, 96), 256, 0, stream>>>(mlp_proj_w + (size_t)l * 3072 * 768, wT, 3072, 768);
        gemm_bf<1><<<dim3(6, 16), 256, 0, stream>>>(h_bf, wT, x, 2048, 768, 3072, mlp_scale, l, nullptr);
    }

    rmsnorm_bf<<<NTOK, 256, 0, stream>>>(x, xn_bf, final_norm_w, 768);
    hipMemsetAsync(Zrow, 0, NTOK * sizeof(float), stream);
    gemm_bf<2><<<dim3(250, 16), 256, 0, stream>>>(xn_bf, embT, nullptr, 2048, 32000, 768, nullptr, 0, Zrow);
    target_kernel<<<512, 256, 0, stream>>>(xn_bf, embT, target_ids, tgt);
    final_reduce<<<1, 256, 0, stream>>>(Zrow, tgt, out);
}